// Round 1
// baseline (128.225 us; speedup 1.0000x reference)
//
#include <hip/hip_runtime.h>
#include <hip/hip_bf16.h>

// SubnetGate = gathered grouped GEMM (B=16384, K=512, N=512, E=8, col 0).
// R3 redesign vs R2:
//  - gemm: BM 128->64 (1024 active blocks = 4/CU), A staged per-wave in
//    REGISTERS (16 exclusive rows/wave, per-lane 32B contiguous gather) --
//    no A LDS, no A pack/ds_write; B double-buffered global_load_lds with
//    ONE barrier per k-step (loads for kt+1 fly under kt's MFMAs).
//  - expert->XCD pinning: e = bid&7, nt fastest -> nt-mates share L2,
//    expert Wtile (512KB bf16) L2-resident per XCD; nontemporal C stores.
//  - prep: tile build split 4x (1024 blocks, 4KB LDS quarter-tiles, same
//    final layout) + 64 scatter blocks; zero kernel -> hipMemsetAsync.
//
// ws layout:
//   [0,        32)        int counts[8]
//   [4096,     528384)    int rowlist[8][16384]
//   [528384,   4722688)   ushort Wtile[8][4 nt][8 kt][128n x 64k bf16, swizzled]

#define NROWS   16384
#define KDIM    512
#define NDIM    512
#define NEXP    8
#define BM      64
#define BN      128
#define BK      64
#define NT_PER  4
#define KT_PER  8
#define TILE_ELEMS (BN * BK)          // 8192 bf16 = 16KB
#define WS_ROWLIST_OFF 4096
#define WS_WT_OFF      (4096 + NEXP * NROWS * 4)

typedef __bf16        bf16x8 __attribute__((ext_vector_type(8)));
typedef float         f32x4  __attribute__((ext_vector_type(4)));
typedef unsigned int  u32x4  __attribute__((ext_vector_type(4)));

__device__ __forceinline__ unsigned int f2bf_u(float f) {
    unsigned int u = __builtin_bit_cast(unsigned int, f);
    return (u + 0x7FFFu + ((u >> 16) & 1u)) >> 16;   // RNE f32->bf16
}

__device__ __forceinline__ void gl_lds16(const void* g, void* l) {
    __builtin_amdgcn_global_load_lds(
        (const __attribute__((address_space(1))) unsigned int*)g,
        (__attribute__((address_space(3))) unsigned int*)l, 16, 0, 0);
}

__device__ __forceinline__ bf16x8 pack_bf8(f32x4 lo, f32x4 hi) {
    u32x4 w;
    w.x = f2bf_u(lo.x) | (f2bf_u(lo.y) << 16);
    w.y = f2bf_u(lo.z) | (f2bf_u(lo.w) << 16);
    w.z = f2bf_u(hi.x) | (f2bf_u(hi.y) << 16);
    w.w = f2bf_u(hi.z) | (f2bf_u(hi.w) << 16);
    return __builtin_bit_cast(bf16x8, w);
}

// blocks [0,1024): build one quarter (32 n-cols) of a 16KB swizzled B-tile.
//   tile = bid>>2 = e*32 + nt*8 + kt; qq = bid&3 selects n in [qq*32, qq*32+32).
//   granule (n, g) holds W[e][kt*64+g*8 .. +8][nt*128+n] bf16, final global
//   granule index gi = n*8 + (g^(n&7))  (byte offset gi*16) -- identical
//   layout to R2, conflict-free for gemm's fragment ds_reads.
// blocks [1024,1088): histogram+scatter 256 rows each into per-expert rowlists.
__global__ void prep_kernel(const float* __restrict__ W,
                            const int* __restrict__ groups,
                            int* __restrict__ gcnt,
                            int* __restrict__ rowlist,
                            unsigned short* __restrict__ Wtile) {
    __shared__ __align__(16) unsigned short tl4[32 * 64];  // 4KB quarter-tile
    __shared__ int lcnt[NEXP];
    __shared__ int lbase[NEXP];
    const int bid = blockIdx.x;
    const int tid = threadIdx.x;

    if (bid < 1024) {
        const int tile = bid >> 2;        // e*32 + nt*8 + kt
        const int qq   = bid & 3;
        const int e  = tile >> 5;
        const int nt = (tile >> 3) & 3;
        const int kt = tile & 7;
        const float* Wb = W + (size_t)e * (KDIM * NDIM);

        const int n   = qq * 32 + (tid & 31);   // lanes: consecutive n -> coalesced
        const int g   = tid >> 5;               // 0..7
        const int col = nt * BN + n;
        unsigned int p[4];
        #pragma unroll
        for (int jj = 0; jj < 4; ++jj) {
            int k0 = kt * BK + g * 8 + jj * 2;
            unsigned int lo = f2bf_u(Wb[(size_t)k0 * NDIM + col]);
            unsigned int hi = f2bf_u(Wb[(size_t)(k0 + 1) * NDIM + col]);
            p[jj] = lo | (hi << 16);
        }
        *(u32x4*)&tl4[(n & 31) * 64 + (g ^ (n & 7)) * 8] = *(const u32x4*)p;
        __syncthreads();
        // local granule tid = (n' = tid>>3, swz = tid&7); global gi = qq*256+tid
        unsigned short* dst = Wtile + (size_t)tile * TILE_ELEMS
                                    + ((size_t)qq * 256 + tid) * 8;
        *(u32x4*)dst = *(const u32x4*)&tl4[tid * 8];
    } else {
        const int base = (bid - 1024) * 256;
        if (tid < NEXP) lcnt[tid] = 0;
        __syncthreads();
        int r = base + tid;
        int e = groups[r * 2] & 7;       // group_col = 0; mask for mem safety
        int pos = atomicAdd(&lcnt[e], 1);
        __syncthreads();
        if (tid < NEXP) lbase[tid] = atomicAdd(&gcnt[tid], lcnt[tid]);
        __syncthreads();
        rowlist[e * NROWS + lbase[e] + pos] = r;
    }
}

// Block = (expert e = bid&7 -> XCD-pinned, nt fastest, then mt).
// 4 waves; wave w owns rows [w*16, w*16+16) x all 128 cols.
// A: per-lane register gather -- lane (q,l15) reads x[rl[w*16+l15]]
//    cols kt*64 + {q*8..+8, 32+q*8..+8} (two 32B contiguous chunks; the 4
//    q-lanes of a row cover 128B contiguous). f32->bf16 cvt in regs.
// B: double-buffered async global_load_lds; ONE __syncthreads per k-step
//    (its vmcnt(0) drain is the only wait; kt+1 loads hide under kt MFMAs).
__global__ __launch_bounds__(256, 4)
void gemm_kernel(const float* __restrict__ x,
                 const int* __restrict__ counts,
                 const int* __restrict__ rowlist,
                 const unsigned short* __restrict__ Wtile,
                 const float* __restrict__ bias,
                 float* __restrict__ out) {
    __shared__ __align__(16) unsigned short Bsm[2][TILE_ELEMS];  // 32KB

    const int bid = blockIdx.x;
    const int e   = bid & 7;
    const int j   = bid >> 3;
    const int nt  = j & 3;
    const int mt  = j >> 2;
    const int cnt = counts[e];
    const int rb  = mt * BM;
    if (rb >= cnt) return;
    int m_valid = cnt - rb;
    if (m_valid > BM) m_valid = BM;
    const int* rl = rowlist + e * NROWS + rb;

    const int tid = threadIdx.x;
    const int w   = tid >> 6;
    const int ln  = tid & 63;
    const int q   = ln >> 4;
    const int l15 = ln & 15;

    const int am = w * 16 + l15;
    const float* aptr = x + (size_t)rl[(am < m_valid) ? am : 0] * KDIM + q * 8;

    const unsigned short* wt =
        Wtile + (size_t)((e * NT_PER + nt) * KT_PER) * TILE_ELEMS;

    f32x4 a0, a1, a2, a3;
    f32x4 acc[8];
    #pragma unroll
    for (int ni = 0; ni < 8; ++ni) acc[ni] = (f32x4){0.f, 0.f, 0.f, 0.f};

    // ---- prologue: stage B(0) + A(0)
    #pragma unroll
    for (int i = 0; i < 4; ++i) {
        int off = (i * 256 + tid) * 8;
        gl_lds16(wt + off, &Bsm[0][off]);
    }
    a0 = *(const f32x4*)aptr;
    a1 = *(const f32x4*)(aptr + 4);
    a2 = *(const f32x4*)(aptr + 32);
    a3 = *(const f32x4*)(aptr + 36);

    for (int kt = 0; kt < KT_PER; ++kt) {
        __syncthreads();   // vmcnt(0) drain: B(kt) in Bsm[kt&1], A(kt) in regs
        if (kt < KT_PER - 1) {   // issue B(kt+1) into the other buffer
            const unsigned short* src = wt + (size_t)(kt + 1) * TILE_ELEMS;
            unsigned short* dstl = Bsm[(kt + 1) & 1];
            #pragma unroll
            for (int i = 0; i < 4; ++i) {
                int off = (i * 256 + tid) * 8;
                gl_lds16(src + off, dstl + off);
            }
        }
        bf16x8 af0 = pack_bf8(a0, a1);   // g = q      (k-offset q*8)
        bf16x8 af1 = pack_bf8(a2, a3);   // g = 4+q    (k-offset 32+q*8)
        if (kt < KT_PER - 1) {           // issue A(kt+1) (regs free after cvt)
            const float* s = aptr + (kt + 1) * BK;
            a0 = *(const f32x4*)s;
            a1 = *(const f32x4*)(s + 4);
            a2 = *(const f32x4*)(s + 32);
            a3 = *(const f32x4*)(s + 36);
        }
        const unsigned short* bcur = Bsm[kt & 1];
        #pragma unroll
        for (int ni = 0; ni < 8; ++ni) {
            int n = ni * 16 + l15;
            bf16x8 b0 = *(const bf16x8*)&bcur[n * 64 + (q ^ (n & 7)) * 8];
            acc[ni] = __builtin_amdgcn_mfma_f32_16x16x32_bf16(af0, b0, acc[ni], 0, 0, 0);
        }
        #pragma unroll
        for (int ni = 0; ni < 8; ++ni) {
            int n = ni * 16 + l15;
            bf16x8 b1 = *(const bf16x8*)&bcur[n * 64 + ((4 + q) ^ (n & 7)) * 8];
            acc[ni] = __builtin_amdgcn_mfma_f32_16x16x32_bf16(af1, b1, acc[ni], 0, 0, 0);
        }
    }

    // ---- epilogue: +bias, masked nontemporal scatter (C/D: col=l15, row=q*4+r)
    int grow[4];
    #pragma unroll
    for (int r = 0; r < 4; ++r) {
        int mloc = w * 16 + q * 4 + r;
        grow[r] = (mloc < m_valid) ? rl[mloc] : -1;
    }
    const int ncol0 = nt * BN;
    #pragma unroll
    for (int ni = 0; ni < 8; ++ni) {
        int col = ncol0 + ni * 16 + l15;
        float bv = bias[e * NDIM + col];
        #pragma unroll
        for (int r = 0; r < 4; ++r)
            if (grow[r] >= 0)
                __builtin_nontemporal_store(acc[ni][r] + bv,
                                            &out[(size_t)grow[r] * NDIM + col]);
    }
}

extern "C" void kernel_launch(void* const* d_in, const int* in_sizes, int n_in,
                              void* d_out, int out_size, void* d_ws, size_t ws_size,
                              hipStream_t stream) {
    const float* x      = (const float*)d_in[0];   // (16384, 512) f32
    const int*   groups = (const int*)d_in[1];     // (16384, 2) i32
    const float* W      = (const float*)d_in[2];   // (8, 512, 512) f32
    const float* b      = (const float*)d_in[3];   // (8, 512) f32
    float*       out    = (float*)d_out;           // (16384, 512) f32

    char* ws = (char*)d_ws;
    int*            counts  = (int*)ws;
    int*            rowlist = (int*)(ws + WS_ROWLIST_OFF);
    unsigned short* Wtile   = (unsigned short*)(ws + WS_WT_OFF);

    hipMemsetAsync(counts, 0, NEXP * sizeof(int), stream);
    prep_kernel<<<1088, 256, 0, stream>>>(W, groups, counts, rowlist, Wtile);
    // grid: 8 experts (XCD-pinned via bid&7) x 256 m-tiles x 4 n-tiles;
    // inactive (e,mt) blocks exit on counts[e]. Active ~1024 = 4 blocks/CU.
    gemm_kernel<<<8192, 256, 0, stream>>>(x, counts, rowlist, Wtile, b, out);
}